// Round 12
// baseline (593.654 us; speedup 1.0000x reference)
//
#include <hip/hip_runtime.h>
#include <hip/hip_bf16.h>
#include <stdint.h>

#define D 1024
#define NSUP 256
#define ROWS 16384      // 4*4096
#define MB 64           // rows per block
#define LTHREADS 1024   // 16 waves -> 4 waves/SIMD
#define LGRID (ROWS / MB)   // 256 blocks = 1/CU
#define LDS_BYTES 131072    // h[64][1024] bf16 swizzled; w aliased into rows 48-63
#define WBASE 98304         // 48*2048: w[64][256] bf16 region (old-h rows 48-63)

typedef __attribute__((__ext_vector_type__(8))) __bf16 bf16x8;
typedef __attribute__((__ext_vector_type__(4))) float f32x4;
typedef __attribute__((__ext_vector_type__(4))) uint32_t u32x4;

#define MFMA16(a, b, c) __builtin_amdgcn_mfma_f32_16x16x32_bf16((a), (b), (c), 0, 0, 0)

static __device__ __forceinline__ float bb2f(uint32_t b) {
    union { uint32_t u; float f; } c; c.u = b; return c.f;
}
static __device__ __forceinline__ uint32_t bfbits(float f) {
    __bf16 b = (__bf16)f;
    return (uint32_t)*(uint16_t*)&b;
}

__global__ void cast_k_kernel(const float* __restrict__ K, __bf16* __restrict__ Kb) {
    int i = (blockIdx.x * 256 + threadIdx.x) * 4;
    float4 v = *(const float4*)(K + i);
    __bf16 o[4] __attribute__((aligned(8)));
    o[0] = (__bf16)v.x; o[1] = (__bf16)v.y; o[2] = (__bf16)v.z; o[3] = (__bf16)v.w;
    *(uint2*)(Kb + i) = *(const uint2*)o;
}

// V [4][256][1024] f32 -> Vt [4][1024][256] bf16
__global__ void transpose_v_kernel(const float* __restrict__ V, __bf16* __restrict__ Vt) {
    __shared__ __bf16 tile[64][72];
    int l = blockIdx.z;
    int d0 = blockIdx.x * 64, n0 = blockIdx.y * 64;
    const float* Vl = V + (size_t)l * NSUP * D;
    __bf16* Vtl = Vt + (size_t)l * D * NSUP;
    for (int j = 0; j < 16; ++j) {
        int idx = j * 256 + threadIdx.x;
        int n_l = idx >> 6, d_l = idx & 63;
        tile[d_l][n_l] = (__bf16)Vl[(size_t)(n0 + n_l) * D + d0 + d_l];
    }
    __syncthreads();
    for (int j = 0; j < 16; ++j) {
        int idx = j * 256 + threadIdx.x;
        int d_l = idx >> 6, n_l = idx & 63;
        Vtl[(size_t)(d0 + d_l) * NSUP + n0 + n_l] = tile[d_l][n_l];
    }
}

// All 4 layers fused; h[64][1024] bf16 resident in 128K dynamic LDS (XOR-swizzled
// rows). 1024 thr / 16 waves / 1 block per CU (4 waves/SIMD). MB=64 halves the
// aggregate K/V L2/L3 streaming vs MB=32 (256 blocks x 4MB = 1 GB).
// Per layer: [rn-pass: row sq-norms from LDS h -> rnred | Phase A MFMA w/ K ring]
// bar1 [Phase B: exp(score*rn), partials] bar2 [S totals, w -> WBASE] bar3
// [Phase C 4x16-col chunks w/ V ring; new-h rows 0-47 immediate, rows 48-63
// packed in 8 regs] bar4 [deferred rows 48-63 -> old w region] bar5.
// Final layer: direct f32 stores. No softmax max-pass (exp2 arg <= ~50, f32-safe).
// REGISTER RULE: plain __launch_bounds__ ONLY. A second arg or waves_per_eu
// pins VGPR=64 on this toolchain (CUDA blocks-per-SM semantics) -> spills.
// Plain (1024) forces the compiler to fit 1 block -> up to 128 VGPR, no spill.
__global__ void __launch_bounds__(LTHREADS)
fused4_kernel(const float* __restrict__ x, float* __restrict__ out,
              const __bf16* __restrict__ Kb, const __bf16* __restrict__ Vt) {
    extern __shared__ __align__(16) char pool[];
    __shared__ float rnred[MB];
    const int tid = threadIdx.x;
    const int lane = tid & 63;
    const int wv = tid >> 6;            // wave 0..15
    const int llo = lane & 15, lhi = lane >> 4;
    const int swzk = (llo & 7) << 4;    // swizzle key for rows *16+llo
    const int row0 = blockIdx.x * MB;

    // ---- stage x -> RAW bf16 h (swizzled); rn computed later from LDS ----
    {
        const int srow = tid >> 4, c16 = tid & 15;   // 64 rows x 16 thr
        const float* xr = x + (size_t)(row0 + srow) * D;
        const int sk = (srow & 7) << 4;
        #pragma unroll
        for (int q = 0; q < 16; ++q) {
            float4 v = *(const float4*)(xr + (c16 + q * 16) * 4);
            __bf16 t[4] __attribute__((aligned(8)));
            t[0] = (__bf16)v.x; t[1] = (__bf16)v.y; t[2] = (__bf16)v.z; t[3] = (__bf16)v.w;
            *(uint2*)(pool + srow * 2048 + (((c16 + q * 16) * 8) ^ sk)) = *(const uint2*)t;
        }
    }
    __syncthreads();

    #pragma unroll 1
    for (int l = 0; l < 4; ++l) {
        // ---- rn-pass: ||h_row||^2 from LDS (wave wv owns rows wv*4..+4) ----
        #pragma unroll
        for (int rr = 0; rr < 4; ++rr) {
            int row = wv * 4 + rr;
            const char* rb = pool + row * 2048;
            int key = (row & 7) << 4;
            float s = 0.f;
            #pragma unroll
            for (int h2 = 0; h2 < 2; ++h2) {
                u32x4 u = *(const u32x4*)(rb + ((lane * 32 + h2 * 16) ^ key));
                #pragma unroll
                for (int j = 0; j < 4; ++j) {
                    float f0 = bb2f(u[j] << 16), f1 = bb2f(u[j] & 0xffff0000u);
                    s += f0 * f0 + f1 * f1;
                }
            }
            s += __shfl_xor(s, 1); s += __shfl_xor(s, 2); s += __shfl_xor(s, 4);
            s += __shfl_xor(s, 8); s += __shfl_xor(s, 16); s += __shfl_xor(s, 32);
            if (lane == 0) rnred[row] = s;
        }

        // ---- Phase A: scores[64x256] = h @ K^T; wave owns cols [wv*16,+16) ----
        f32x4 acc[4];
        #pragma unroll
        for (int rf = 0; rf < 4; ++rf) acc[rf] = (f32x4){0.f, 0.f, 0.f, 0.f};
        const __bf16* kb0 = Kb + (size_t)l * NSUP * D + (size_t)(wv * 16 + llo) * D + lhi * 8;
        bf16x8 kb[4];
        #pragma unroll
        for (int p = 0; p < 3; ++p) kb[p] = *(const bf16x8*)(kb0 + p * 32);
        #pragma unroll
        for (int k = 0; k < 32; ++k) {
            if (k < 29) kb[(k + 3) & 3] = *(const bf16x8*)(kb0 + (k + 3) * 32);
            #pragma unroll
            for (int rf = 0; rf < 4; ++rf) {
                bf16x8 a = *(const bf16x8*)(pool + (rf * 16 + llo) * 2048
                                            + ((k * 64 + lhi * 16) ^ swzk));
                acc[rf] = MFMA16(a, kb[k & 3], acc[rf]);
            }
        }
        __syncthreads();   // bar1: A + rn-pass done; old h dead

        // ---- Phase B: exp(score * rn) + wave partial sums -> pool[0:4K) ----
        #pragma unroll
        for (int rf = 0; rf < 4; ++rf)
            #pragma unroll
            for (int r = 0; r < 4; ++r) {
                int row = rf * 16 + lhi * 4 + r;
                float rn = 1.f / (sqrtf(rnred[row]) + 1e-9f);
                float e = exp2f(acc[rf][r] * rn * 1.44269504f);
                acc[rf][r] = e;
                float s = e;
                s += __shfl_xor(s, 1); s += __shfl_xor(s, 2);
                s += __shfl_xor(s, 4); s += __shfl_xor(s, 8);
                if (llo == 0) *(float*)(pool + row * 64 + wv * 4) = s;
            }
        __syncthreads();   // bar2: exp partials visible

        #pragma unroll
        for (int rf = 0; rf < 4; ++rf)
            #pragma unroll
            for (int r = 0; r < 4; ++r) {
                int row = rf * 16 + lhi * 4 + r;
                const f32x4* rp = (const f32x4*)(pool + row * 64);
                f32x4 s0 = rp[0], s1 = rp[1], s2 = rp[2], s3 = rp[3];
                float S = (s0[0] + s0[1] + s0[2] + s0[3]) + (s1[0] + s1[1] + s1[2] + s1[3])
                        + (s2[0] + s2[1] + s2[2] + s2[3]) + (s3[0] + s3[1] + s3[2] + s3[3]);
                float inv = 1.f / S;
                int col = wv * 16 + llo;
                *(__bf16*)(pool + WBASE + row * 512 + ((col * 2) ^ ((row & 7) << 4))) =
                    (__bf16)(acc[rf][r] * inv);
            }
        __syncthreads();   // bar3: w visible

        // ---- Phase C: out[64x1024] = w @ V; wave d-cols [wv*64,+64), 4x16 ----
        uint32_t def[4][2];   // deferred rows 48-63 (rf=3), bf16-packed
        #pragma unroll
        for (int ch = 0; ch < 4; ++ch) {
            f32x4 acc2[4];
            #pragma unroll
            for (int rf = 0; rf < 4; ++rf) acc2[rf] = (f32x4){0.f, 0.f, 0.f, 0.f};
            const __bf16* vt0 = Vt + (size_t)l * D * NSUP
                              + (size_t)(wv * 64 + ch * 16 + llo) * NSUP + lhi * 8;
            bf16x8 vb[4];
            #pragma unroll
            for (int p = 0; p < 3; ++p) vb[p] = *(const bf16x8*)(vt0 + p * 32);
            #pragma unroll
            for (int k = 0; k < 8; ++k) {
                if (k < 5) vb[(k + 3) & 3] = *(const bf16x8*)(vt0 + (k + 3) * 32);
                #pragma unroll
                for (int rf = 0; rf < 4; ++rf) {
                    bf16x8 aw = *(const bf16x8*)(pool + WBASE + (rf * 16 + llo) * 512
                                                 + ((k * 64 + lhi * 16) ^ swzk));
                    acc2[rf] = MFMA16(aw, vb[k & 3], acc2[rf]);
                }
            }
            int col = wv * 64 + ch * 16 + llo;
            if (l < 3) {
                // rows 0-47 (rf 0..2) immediate; rows 48-63 (rf 3) deferred
                #pragma unroll
                for (int rf = 0; rf < 3; ++rf)
                    #pragma unroll
                    for (int r = 0; r < 4; ++r) {
                        int row = rf * 16 + lhi * 4 + r;
                        *(__bf16*)(pool + row * 2048 + ((col * 2) ^ ((row & 7) << 4))) =
                            (__bf16)acc2[rf][r];
                    }
                def[ch][0] = bfbits(acc2[3][0]) | (bfbits(acc2[3][1]) << 16);
                def[ch][1] = bfbits(acc2[3][2]) | (bfbits(acc2[3][3]) << 16);
            } else {
                // final: direct f32 stores (16-lane x 4B = 64B dense runs)
                #pragma unroll
                for (int rf = 0; rf < 4; ++rf)
                    #pragma unroll
                    for (int r = 0; r < 4; ++r) {
                        int row = rf * 16 + lhi * 4 + r;
                        out[(size_t)(row0 + row) * D + col] = acc2[rf][r];
                    }
            }
        }

        if (l < 3) {
            __syncthreads();   // bar4: all w reads done -> w region dead
            #pragma unroll
            for (int ch = 0; ch < 4; ++ch) {
                int col = wv * 64 + ch * 16 + llo;
                #pragma unroll
                for (int rp = 0; rp < 2; ++rp) {
                    uint32_t pk = def[ch][rp];
                    int re = 48 + lhi * 4 + rp * 2;
                    int ro = re + 1;
                    *(uint16_t*)(pool + re * 2048 + ((col * 2) ^ ((re & 7) << 4))) =
                        (uint16_t)(pk & 0xffff);
                    *(uint16_t*)(pool + ro * 2048 + ((col * 2) ^ ((ro & 7) << 4))) =
                        (uint16_t)(pk >> 16);
                }
            }
            __syncthreads();   // bar5: h complete for next layer
        }
    }
}

extern "C" void kernel_launch(void* const* d_in, const int* in_sizes, int n_in,
                              void* d_out, int out_size, void* d_ws, size_t ws_size,
                              hipStream_t stream) {
    const float* x = (const float*)d_in[0];
    const float* keys = (const float*)d_in[1];
    const float* values = (const float*)d_in[2];
    float* out = (float*)d_out;

    char* ws = (char*)d_ws;
    __bf16* Kb = (__bf16*)(ws);             // 4*256*1024*2 = 2 MB
    __bf16* Vt = (__bf16*)(ws + 2097152);   // 4*1024*256*2 = 2 MB

    (void)hipFuncSetAttribute((const void*)fused4_kernel,
                              hipFuncAttributeMaxDynamicSharedMemorySize, LDS_BYTES);

    cast_k_kernel<<<1024, 256, 0, stream>>>(keys, Kb);
    transpose_v_kernel<<<dim3(16, 4, 4), 256, 0, stream>>>(values, Vt);
    fused4_kernel<<<LGRID, LTHREADS, LDS_BYTES, stream>>>(x, out, Kb, Vt);
}

// Round 13
// 310.805 us; speedup vs baseline: 1.9101x; 1.9101x over previous
//
#include <hip/hip_runtime.h>
#include <hip/hip_bf16.h>
#include <stdint.h>

#define D 1024
#define NSUP 256
#define ROWS 16384      // 4*4096
#define MB 32           // rows per block
#define LTHREADS 512    // 8 waves; ONLY config with sane VGPR budget (see rule)
#define LGRID (ROWS / MB)   // 512 blocks

typedef __attribute__((__ext_vector_type__(8))) __bf16 bf16x8;
typedef __attribute__((__ext_vector_type__(4))) float f32x4;

#define MFMA16(a, b, c) __builtin_amdgcn_mfma_f32_16x16x32_bf16((a), (b), (c), 0, 0, 0)

static __device__ __forceinline__ uint16_t bf16bits(float f) {
    __bf16 b = (__bf16)f;
    return *(uint16_t*)&b;
}

__global__ void cast_k_kernel(const float* __restrict__ K, __bf16* __restrict__ Kb) {
    int i = (blockIdx.x * 256 + threadIdx.x) * 4;
    float4 v = *(const float4*)(K + i);
    __bf16 o[4] __attribute__((aligned(8)));
    o[0] = (__bf16)v.x; o[1] = (__bf16)v.y; o[2] = (__bf16)v.z; o[3] = (__bf16)v.w;
    *(uint2*)(Kb + i) = *(const uint2*)o;
}

// V [4][256][1024] f32 -> Vt [4][1024][256] bf16
__global__ void transpose_v_kernel(const float* __restrict__ V, __bf16* __restrict__ Vt) {
    __shared__ __bf16 tile[64][72];
    int l = blockIdx.z;
    int d0 = blockIdx.x * 64, n0 = blockIdx.y * 64;
    const float* Vl = V + (size_t)l * NSUP * D;
    __bf16* Vtl = Vt + (size_t)l * D * NSUP;
    for (int j = 0; j < 16; ++j) {
        int idx = j * 256 + threadIdx.x;
        int n_l = idx >> 6, d_l = idx & 63;
        tile[d_l][n_l] = (__bf16)Vl[(size_t)(n0 + n_l) * D + d0 + d_l];
    }
    __syncthreads();
    for (int j = 0; j < 16; ++j) {
        int idx = j * 256 + threadIdx.x;
        int d_l = idx >> 6, n_l = idx & 63;
        Vtl[(size_t)(d0 + d_l) * NSUP + n0 + n_l] = tile[d_l][n_l];
    }
}

// One CleanUpKV layer. 512 thr / 8 waves / 32 rows / LDS ~50K -> 2 blocks/CU
// (16 waves/CU for TLP latency hiding).
// h between layers: RAW bf16, stored PRE-SWIZZLED in global (element (row,col)
// at byte row*2048 + ((col*2) ^ ((row&7)<<4))) so staging is a pure linear
// global_load_lds copy and MFMA reads are bank-conflict-free.
// rn (1/||h_row||) passed between layers via rnbuf (computed in epilogue from
// f32 accumulators, folded into next layer's softmax exp) -> no normalize pass.
// No softmax max-pass: |score*rn| <= |k_row| ~ 34 -> exp2 arg <= 50, f32-safe.
// HARD-WON RULES (rounds 3-12): (1) 1024-thr blocks pin VGPR=64 + spill
// catastrophically; 512 + plain __launch_bounds__(512) gives 80-128, no spill.
// Never add a 2nd launch_bounds arg or waves_per_eu. (2) LDS <= ~51.7K -> 2
// blocks/CU; >=64K -> 1 block. Fused h-resident (64K) is thus infeasible.
template<bool IN_F32, bool OUT_F32>
__global__ void __launch_bounds__(LTHREADS)
layer_kernel(const void* __restrict__ h_in, void* __restrict__ h_out,
             const __bf16* __restrict__ Kb, const __bf16* __restrict__ Vt,
             float* __restrict__ rnbuf) {
    __shared__ __align__(16) char pool[49152];   // buf0 16K | buf1 16K | w 16K
    __shared__ float red[MB][8];
    __shared__ float rnin[MB];
    char* wbuf = pool + 32768;

    const int tid = threadIdx.x;
    const int lane = tid & 63;
    const int wv = tid >> 6;            // wave 0..7
    const int llo = lane & 15, lhi = lane >> 4;
    const int swzk = (llo & 7) << 4;    // swizzle key for rows *16+llo
    const int row0 = blockIdx.x * MB;

    // ---- rn input: layer0 computes from x; others load from rnbuf ----
    if constexpr (IN_F32) {
        const float4* x4 = (const float4*)h_in;
        #pragma unroll
        for (int rr = 0; rr < 4; ++rr) {
            int row = wv * 4 + rr;
            const float4* p = x4 + (size_t)(row0 + row) * 256;
            float s = 0.f;
            #pragma unroll
            for (int j = 0; j < 4; ++j) {
                float4 v = p[j * 64 + lane];
                s += v.x * v.x + v.y * v.y + v.z * v.z + v.w * v.w;
            }
            #pragma unroll
            for (int off = 1; off < 64; off <<= 1) s += __shfl_xor(s, off);
            if (lane == 0) rnin[row] = 1.f / (sqrtf(s) + 1e-9f);
        }
        __syncthreads();   // rnin ready for scaled staging
    } else {
        if (tid < MB) rnin[tid] = rnbuf[row0 + tid];
    }

    // ---- staging of one 32x256-col chunk (16KB) ----
    auto stage = [&](int dc) {
        char* buf = pool + (dc & 1) * 16384;
        if constexpr (IN_F32) {
            // f32 x -> normalized bf16, swizzled ds_write
            int srow = tid >> 4, c16 = tid & 15;
            int key = (srow & 7) << 4;
            const float4* p = (const float4*)((const float*)h_in
                              + (size_t)(row0 + srow) * D + dc * 256 + c16 * 16);
            float rn = rnin[srow];
            __bf16 t[16] __attribute__((aligned(16)));
            #pragma unroll
            for (int q = 0; q < 4; ++q) {
                float4 v = p[q];
                t[4 * q + 0] = (__bf16)(v.x * rn); t[4 * q + 1] = (__bf16)(v.y * rn);
                t[4 * q + 2] = (__bf16)(v.z * rn); t[4 * q + 3] = (__bf16)(v.w * rn);
            }
            int b0 = c16 * 32;
            *(bf16x8*)(buf + srow * 512 + (b0 ^ key))        = *(const bf16x8*)(t);
            *(bf16x8*)(buf + srow * 512 + ((b0 + 16) ^ key)) = *(const bf16x8*)(t + 8);
        } else {
            // pure copy: global image already swizzled; linear 16B/lane
            #pragma unroll
            for (int c = 0; c < 2; ++c) {
                int L = (c * 512 + tid) * 16;
                int row = L >> 9;
                int b = L & 511;
                const char* g = (const char*)h_in + (size_t)(row0 + row) * 2048 + dc * 512 + b;
                __builtin_amdgcn_global_load_lds(
                    (const __attribute__((address_space(1))) uint32_t*)g,
                    (__attribute__((address_space(3))) uint32_t*)(buf + L), 16, 0, 0);
            }
        }
    };

    // ---------- Phase A: scores[32x256] = h @ K^T; wave cols [wv*32,+32) ----------
    f32x4 acc[2][2];
    #pragma unroll
    for (int rf = 0; rf < 2; ++rf)
        #pragma unroll
        for (int cf = 0; cf < 2; ++cf)
            acc[rf][cf] = (f32x4){0.f, 0.f, 0.f, 0.f};

    stage(0);
    __syncthreads();
    #pragma unroll 1
    for (int dc = 0; dc < 4; ++dc) {
        if (dc < 3) stage(dc + 1);   // prefetch; drained by the barrier AFTER compute
        const char* hb = pool + (dc & 1) * 16384;
        const __bf16* kb0 = Kb + (size_t)(wv * 32 + llo) * D + dc * 256 + lhi * 8;
        bf16x8 kbuf[2][2];
        #pragma unroll
        for (int cf = 0; cf < 2; ++cf)
            kbuf[0][cf] = *(const bf16x8*)(kb0 + (size_t)cf * 16 * D);
        #pragma unroll
        for (int kk = 0; kk < 8; ++kk) {
            if (kk < 7) {
                #pragma unroll
                for (int cf = 0; cf < 2; ++cf)
                    kbuf[(kk + 1) & 1][cf] = *(const bf16x8*)(kb0 + (size_t)cf * 16 * D + (kk + 1) * 32);
            }
            bf16x8 a0 = *(const bf16x8*)(hb + llo * 512 + ((kk * 64 + lhi * 16) ^ swzk));
            bf16x8 a1 = *(const bf16x8*)(hb + (16 + llo) * 512 + ((kk * 64 + lhi * 16) ^ swzk));
            #pragma unroll
            for (int cf = 0; cf < 2; ++cf) {
                acc[0][cf] = MFMA16(a0, kbuf[kk & 1][cf], acc[0][cf]);
                acc[1][cf] = MFMA16(a1, kbuf[kk & 1][cf], acc[1][cf]);
            }
        }
        __syncthreads();   // drains prefetch dc+1 + protects dbuf reuse
    }

    // ---------- Phase B: softmax (rn folded, no max-pass) ----------
    float ee[2][2][4];
    #pragma unroll
    for (int rf = 0; rf < 2; ++rf)
        #pragma unroll
        for (int r = 0; r < 4; ++r) {
            int row = rf * 16 + lhi * 4 + r;
            float sc = (IN_F32 ? 1.f : rnin[row]) * 1.44269504f;
            float e0 = exp2f(acc[rf][0][r] * sc);
            float e1 = exp2f(acc[rf][1][r] * sc);
            ee[rf][0][r] = e0; ee[rf][1][r] = e1;
            float s = e0 + e1;
            s += __shfl_xor(s, 1); s += __shfl_xor(s, 2);
            s += __shfl_xor(s, 4); s += __shfl_xor(s, 8);
            if (llo == 0) red[row][wv] = s;
        }
    __syncthreads();   // exp partials visible
    #pragma unroll
    for (int rf = 0; rf < 2; ++rf)
        #pragma unroll
        for (int r = 0; r < 4; ++r) {
            int row = rf * 16 + lhi * 4 + r;
            const f32x4* rp = (const f32x4*)&red[row][0];
            f32x4 s0 = rp[0], s1 = rp[1];
            float S = (s0[0] + s0[1] + s0[2] + s0[3]) + (s1[0] + s1[1] + s1[2] + s1[3]);
            float inv = 1.f / S;
            #pragma unroll
            for (int cf = 0; cf < 2; ++cf) {
                int col = wv * 32 + cf * 16 + llo;
                *(__bf16*)(wbuf + row * 512 + ((col * 2) ^ ((row & 7) << 4))) =
                    (__bf16)(ee[rf][cf][r] * inv);
            }
        }
    __syncthreads();   // w visible

    // ---------- Phase C: out[32x1024] = w @ V; wave d-cols [wv*128,+128) ----------
    float sql[2][4];
    #pragma unroll
    for (int rf = 0; rf < 2; ++rf)
        #pragma unroll
        for (int r = 0; r < 4; ++r) sql[rf][r] = 0.f;

    #pragma unroll 1
    for (int ch = 0; ch < 4; ++ch) {
        f32x4 acc2[2][2];
        #pragma unroll
        for (int rf = 0; rf < 2; ++rf)
            #pragma unroll
            for (int c2 = 0; c2 < 2; ++c2)
                acc2[rf][c2] = (f32x4){0.f, 0.f, 0.f, 0.f};
        const __bf16* vt0 = Vt + (size_t)(wv * 128 + ch * 32 + llo) * NSUP + lhi * 8;
        bf16x8 vbuf[2][2];
        #pragma unroll
        for (int c2 = 0; c2 < 2; ++c2)
            vbuf[0][c2] = *(const bf16x8*)(vt0 + (size_t)c2 * 16 * NSUP);
        #pragma unroll
        for (int kk = 0; kk < 8; ++kk) {
            if (kk < 7) {
                #pragma unroll
                for (int c2 = 0; c2 < 2; ++c2)
                    vbuf[(kk + 1) & 1][c2] = *(const bf16x8*)(vt0 + (size_t)c2 * 16 * NSUP + (kk + 1) * 32);
            }
            bf16x8 a0 = *(const bf16x8*)(wbuf + llo * 512 + ((kk * 64 + lhi * 16) ^ swzk));
            bf16x8 a1 = *(const bf16x8*)(wbuf + (16 + llo) * 512 + ((kk * 64 + lhi * 16) ^ swzk));
            #pragma unroll
            for (int c2 = 0; c2 < 2; ++c2) {
                acc2[0][c2] = MFMA16(a0, vbuf[kk & 1][c2], acc2[0][c2]);
                acc2[1][c2] = MFMA16(a1, vbuf[kk & 1][c2], acc2[1][c2]);
            }
        }
        #pragma unroll
        for (int rf = 0; rf < 2; ++rf)
            #pragma unroll
            for (int c2 = 0; c2 < 2; ++c2)
                #pragma unroll
                for (int r = 0; r < 4; ++r) {
                    int row = rf * 16 + lhi * 4 + r;
                    int col = wv * 128 + ch * 32 + c2 * 16 + llo;
                    float v = acc2[rf][c2][r];
                    sql[rf][r] += v * v;
                    if constexpr (OUT_F32) {
                        ((float*)h_out)[(size_t)(row0 + row) * D + col] = v;
                    } else {
                        // raw bf16 h, pre-swizzled global image
                        *(uint16_t*)((char*)h_out + (size_t)(row0 + row) * 2048
                                     + ((col * 2) ^ ((row & 7) << 4))) = bf16bits(v);
                    }
                }
    }

    // ---------- epilogue: next-layer rn from f32 accumulators ----------
    if constexpr (!OUT_F32) {
        #pragma unroll
        for (int rf = 0; rf < 2; ++rf)
            #pragma unroll
            for (int r = 0; r < 4; ++r) {
                float s = sql[rf][r];
                s += __shfl_xor(s, 1); s += __shfl_xor(s, 2);
                s += __shfl_xor(s, 4); s += __shfl_xor(s, 8);
                if (llo == 0) red[rf * 16 + lhi * 4 + r][wv] = s;
            }
        __syncthreads();
        if (tid < MB) {
            const f32x4* rp = (const f32x4*)&red[tid][0];
            f32x4 s0 = rp[0], s1 = rp[1];
            float S = (s0[0] + s0[1] + s0[2] + s0[3]) + (s1[0] + s1[1] + s1[2] + s1[3]);
            rnbuf[row0 + tid] = 1.f / (sqrtf(S) + 1e-9f);
        }
    }
}

extern "C" void kernel_launch(void* const* d_in, const int* in_sizes, int n_in,
                              void* d_out, int out_size, void* d_ws, size_t ws_size,
                              hipStream_t stream) {
    const float* x = (const float*)d_in[0];
    const float* keys = (const float*)d_in[1];
    const float* values = (const float*)d_in[2];
    float* out = (float*)d_out;

    char* ws = (char*)d_ws;
    char*   h  = ws;                            // 16384*2048 = 33554432 B (raw bf16, swizzled)
    __bf16* Kb = (__bf16*)(ws + 33554432);      // 2 MB
    __bf16* Vt = (__bf16*)(ws + 35651584);      // 2 MB
    float*  rn = (float*)(ws + 37748736);       // 64 KB

    cast_k_kernel<<<1024, 256, 0, stream>>>(keys, Kb);
    transpose_v_kernel<<<dim3(16, 4, 4), 256, 0, stream>>>(values, Vt);

    const int LS = NSUP * D;
    layer_kernel<true,  false><<<LGRID, LTHREADS, 0, stream>>>(x, h, Kb,          Vt,          rn);
    layer_kernel<false, false><<<LGRID, LTHREADS, 0, stream>>>(h, h, Kb + LS,     Vt + LS,     rn);
    layer_kernel<false, false><<<LGRID, LTHREADS, 0, stream>>>(h, h, Kb + 2 * LS, Vt + 2 * LS, rn);
    layer_kernel<false, true ><<<LGRID, LTHREADS, 0, stream>>>(h, out, Kb + 3 * LS, Vt + 3 * LS, rn);
}